// Round 2
// baseline (235.163 us; speedup 1.0000x reference)
//
#include <hip/hip_runtime.h>

#define NC 256
#define FH 36
#define FW 36
#define Q4 ((FH*FW)/4)          // 324 float4 per channel tile
#define SCALE (1.0f/16.0f)
#define CPW 4                   // channels per wave
#define CPB 16                  // channels per block (4 waves)

__device__ __forceinline__ float g_fn(float u) {
    // antiderivative of triangular kernel, clipped to [-1, 1]
    u = fminf(1.0f, fmaxf(-1.0f, u));
    if (u < 0.0f) { float t = u + 1.0f; return 0.5f * t * t; }
    else          { float t = 1.0f - u; return 1.0f - 0.5f * t * t; }
}

__global__ __launch_bounds__(256) void filterpool_kernel(
    const float* __restrict__ feat,
    const float* __restrict__ bb,
    float* __restrict__ out)
{
    const int cg   = blockIdx.x;    // channel group of 16: 0..15 (fastest dim)
    const int n    = blockIdx.y;    // roi index 0..127
    const int t    = threadIdx.x;
    const int lane = t & 63;
    const int wave = t >> 6;        // 0..3
    const int c0   = cg * CPB + wave * CPW;

    __shared__ float wx[FW];
    __shared__ float wy[FH];

    const float bx = bb[n*4+0], by = bb[n*4+1];
    const float bw = bb[n*4+2], bh = bb[n*4+3];
    const float x0 = bx * SCALE,        y0 = by * SCALE;
    const float x1 = (bx + bw) * SCALE, y1 = (by + bh) * SCALE;

    if (t < FW) {
        wx[t] = g_fn(x1 - (float)t) - g_fn(x0 - (float)t);
    } else if (t < FW + FH) {
        int h = t - FW;
        wy[h] = g_fn(y1 - (float)h) - g_fn(y0 - (float)h);
    }
    __syncthreads();

    // Wave reduces 4 contiguous 36x36 channel tiles with 4 independent
    // accumulators (4 parallel load streams -> 20 outstanding float4 in the
    // unrolled body). 36/4 = 9 float4 per row: h = q/9, w0 = (q%9)*4.
    const float4* f0 = (const float4*)(feat + ((size_t)n * NC + c0) * (FH * FW));
    float acc0 = 0.f, acc1 = 0.f, acc2 = 0.f, acc3 = 0.f;

    #pragma unroll
    for (int it = 0; it < 5; ++it) {       // 5*64 = 320 of 324
        int q  = lane + it * 64;
        int h  = q / 9;
        int w0 = (q - h * 9) * 4;
        float wyh = wy[h];
        float wa = wx[w0], wb = wx[w0+1], wc = wx[w0+2], wd = wx[w0+3];
        float4 v0 = f0[q];
        float4 v1 = f0[Q4   + q];
        float4 v2 = f0[2*Q4 + q];
        float4 v3 = f0[3*Q4 + q];
        acc0 += wyh * (v0.x*wa + v0.y*wb + v0.z*wc + v0.w*wd);
        acc1 += wyh * (v1.x*wa + v1.y*wb + v1.z*wc + v1.w*wd);
        acc2 += wyh * (v2.x*wa + v2.y*wb + v2.z*wc + v2.w*wd);
        acc3 += wyh * (v3.x*wa + v3.y*wb + v3.z*wc + v3.w*wd);
    }
    if (lane < 4) {                        // tail: q = 320..323 (h=35, w0=lane*4+20... )
        int q  = 320 + lane;
        int h  = q / 9;
        int w0 = (q - h * 9) * 4;
        float wyh = wy[h];
        float wa = wx[w0], wb = wx[w0+1], wc = wx[w0+2], wd = wx[w0+3];
        float4 v0 = f0[q];
        float4 v1 = f0[Q4   + q];
        float4 v2 = f0[2*Q4 + q];
        float4 v3 = f0[3*Q4 + q];
        acc0 += wyh * (v0.x*wa + v0.y*wb + v0.z*wc + v0.w*wd);
        acc1 += wyh * (v1.x*wa + v1.y*wb + v1.z*wc + v1.w*wd);
        acc2 += wyh * (v2.x*wa + v2.y*wb + v2.z*wc + v2.w*wd);
        acc3 += wyh * (v3.x*wa + v3.y*wb + v3.z*wc + v3.w*wd);
    }

    // 64-lane butterfly reduction of all 4 accumulators
    #pragma unroll
    for (int off = 32; off > 0; off >>= 1) {
        acc0 += __shfl_xor(acc0, off, 64);
        acc1 += __shfl_xor(acc1, off, 64);
        acc2 += __shfl_xor(acc2, off, 64);
        acc3 += __shfl_xor(acc3, off, 64);
    }

    if (lane == 0) {
        float bin_w = x1 - x0, bin_h = y1 - y0;
        float area = fmaxf(bin_w, 0.0f) * fmaxf(bin_h, 0.0f);
        float inv  = (area > 0.0f) ? (1.0f / fmaxf(area, 1e-30f)) : 0.0f;
        float4 r = make_float4(acc0 * inv, acc1 * inv, acc2 * inv, acc3 * inv);
        *(float4*)(out + (size_t)n * NC + c0) = r;
    }
}

extern "C" void kernel_launch(void* const* d_in, const int* in_sizes, int n_in,
                              void* d_out, int out_size, void* d_ws, size_t ws_size,
                              hipStream_t stream) {
    const float* feat = (const float*)d_in[0];
    const float* bb   = (const float*)d_in[1];
    float* out        = (float*)d_out;
    dim3 grid(NC / CPB, 128);   // (channel-group-of-16, roi)
    filterpool_kernel<<<grid, 256, 0, stream>>>(feat, bb, out);
}